// Round 10
// baseline (919.470 us; speedup 1.0000x reference)
//
#include <hip/hip_runtime.h>

#define BATCH 65536

typedef __attribute__((ext_vector_type(8))) short bf16x8;
typedef __attribute__((ext_vector_type(4))) float f32x4;

__device__ __forceinline__ unsigned short f2bf(float f) {
  unsigned int u = __float_as_uint(f);
  u += 0x7fffu + ((u >> 16) & 1u);   // RNE (one-time weight builds only)
  return (unsigned short)(u >> 16);
}
// trunc-pack 2 floats -> 1 dword of 2 bf16 (lo in low half), single v_perm_b32
__device__ __forceinline__ unsigned pack_trunc(float lo, float hi) {
  return __builtin_amdgcn_perm(__float_as_uint(hi), __float_as_uint(lo), 0x07060302u);
}

// tanh(o)*sigmoid(u): 2 exp + 1 rcp; lower-bound clamps keep it NaN-proof.
__device__ __forceinline__ float gru_act(float u, float o) {
  u = fmaxf(u, -60.0f);
  o = fmaxf(o, -30.0f);
  float a  = __expf(-u);
  float a2 = __expf(-2.0f * o);
  return (1.0f - a2) * __builtin_amdgcn_rcpf((1.0f + a) * (1.0f + a2));
}

// conv 3x3 SAME on 3x3 grid, unrolled tap value
__device__ __forceinline__ float conv_tap(const float* __restrict__ w, int co, int ci,
                                          int p, int q, int CINTOT) {
  int pi = p / 3, pj = p % 3, qi = q / 3, qj = q % 3;
  int di = qi - pi + 1, dj = qj - pj + 1;
  if ((unsigned)di < 3u && (unsigned)dj < 3u)
    return w[((co * CINTOT + ci) * 3 + di) * 3 + dj];
  return 0.0f;
}

// BT[g][n][k] bf16, n = co*9+p, k = ci*9+q
__global__ void build_bt(const float* __restrict__ wu, const float* __restrict__ wo,
                         unsigned short* __restrict__ BT, int COUT, int CINX, int CINTOT) {
  int NG = COUT * 9, K = CINX * 9;
  int total = 2 * NG * K;
  int e = blockIdx.x * 256 + threadIdx.x;
  if (e >= total) return;
  int g = e / (NG * K);
  int rem = e - g * (NG * K);
  int n = rem / K, k = rem - n * K;
  BT[e] = f2bf(conv_tap(g ? wo : wu, n / 9, k / 9, n % 9, k % 9, CINTOT));
}

// A1 transposed: [g][q][c], c = col n in [0,288), q = input tap in [0,9)
__global__ void build_a1(const float* __restrict__ wu, const float* __restrict__ wo,
                         float* __restrict__ A1) {
  int e = blockIdx.x * 256 + threadIdx.x;
  if (e >= 5184) return;
  int g = e / 2592;
  int rem = e - g * 2592;
  int q = rem / 288, c = rem - q * 288;
  A1[e] = conv_tap(g ? wo : wu, c / 9, 0, c % 9, q, 33);
}

// ---------------- LDS layout (bytes), lifetimes barrier-separated ----------------
// [0,18688)     x3l (L3 epilogue .. dense) | xl 64x13 f32 [0,3328) (L1 only)
// [18688,23872) wl (post-L2 .. dense)   [23872,23908) blb
// [23936,48512) Bl: 384 rows x 64B (L2), 288 rows (L3)
#define OFF_X3L 0
#define OFF_XL 0
#define OFF_WL 18688
#define OFF_BLB 23872
#define OFF_BL 23936
#define SMEM_BYTES 48512

__global__ __launch_bounds__(256, 3) void megafused(
    const float* __restrict__ xin, const float* __restrict__ A1,
    const float* __restrict__ b1u, const float* __restrict__ b1o,
    const unsigned short* __restrict__ BT2,
    const float* __restrict__ b2u, const float* __restrict__ b2o,
    const unsigned short* __restrict__ BT3,
    const float* __restrict__ b3u, const float* __restrict__ b3o,
    const float* __restrict__ wd, const float* __restrict__ bd,
    float* __restrict__ x1, float* __restrict__ x2,
    float* __restrict__ x3, float* __restrict__ out) {
  __shared__ __align__(16) char smem[SMEM_BYTES];
  char* Bl = smem + OFF_BL;
  unsigned short* x3l = (unsigned short*)(smem + OFF_X3L);
  float* xl = (float*)(smem + OFF_XL);
  float* wl = (float*)(smem + OFF_WL);
  float* blb = (float*)(smem + OFF_BLB);

  const int tid = threadIdx.x;
  const int lane = tid & 63;
  const int wid = tid >> 6;
  const int lrow = lane & 15;
  const int jc = lane >> 4;
  const int r0 = blockIdx.x * 64;
  const int srow = tid >> 2, spart = tid & 3;

  // L2 B-staging thread-constants: 6 chunks/thread, rows ci*64+srow in [0,384)
  unsigned toffB2[6];
  int wOffB2[6];
#pragma unroll
  for (int ci = 0; ci < 6; ++ci) {
    int row = ci * 64 + srow;
    int bg = (row < 192) ? row : (384 + row);   // BT2 row (gate1 at 576)
    toffB2[ci] = (unsigned)bg * 288u + spart * 8;
    wOffB2[ci] = row * 64 + ((spart ^ ((row >> 1) & 3)) << 4);
  }

  // stage x input (stride 13 floats: avoids 4-way bank alias across row-quarters)
  for (int c = tid; c < 576; c += 256) xl[(c / 9) * 13 + (c % 9)] = xin[(size_t)r0 * 9 + c];
  __syncthreads();

  // issue L2 step-0 B loads (in flight across all of L1)
  bf16x8 pf[6];
#pragma unroll
  for (int ci = 0; ci < 6; ++ci) pf[ci] = *(const bf16x8*)(BT2 + toffB2[ci]);

  // ---- L1: exact fp32, lanes = cols; x1 -> global only (no LDS copy) ----
  {
    float au0[9], ao0[9], au1[9], ao1[9];
    const int c1 = tid, c2 = tid + 256;
    const bool has2 = (c2 < 288);
#pragma unroll
    for (int q = 0; q < 9; ++q) {
      au0[q] = A1[q * 288 + c1];
      ao0[q] = A1[2592 + q * 288 + c1];
      au1[q] = has2 ? A1[q * 288 + c2] : 0.0f;
      ao1[q] = has2 ? A1[2592 + q * 288 + c2] : 0.0f;
    }
    float bu0 = b1u[c1 / 9], bo0 = b1o[c1 / 9];
    float bu1 = has2 ? b1u[c2 / 9] : 0.0f;
    float bo1 = has2 ? b1o[c2 / 9] : 0.0f;
    for (int r = 0; r < 64; ++r) {
      const float4 xv0 = *(const float4*)&xl[r * 13];
      const float4 xv1 = *(const float4*)&xl[r * 13 + 4];
      const float x8 = xl[r * 13 + 8];
      float u0 = bu0, o0 = bo0, u1 = bu1, o1 = bo1;
      u0 = fmaf(au0[0], xv0.x, u0); o0 = fmaf(ao0[0], xv0.x, o0);
      u0 = fmaf(au0[1], xv0.y, u0); o0 = fmaf(ao0[1], xv0.y, o0);
      u0 = fmaf(au0[2], xv0.z, u0); o0 = fmaf(ao0[2], xv0.z, o0);
      u0 = fmaf(au0[3], xv0.w, u0); o0 = fmaf(ao0[3], xv0.w, o0);
      u0 = fmaf(au0[4], xv1.x, u0); o0 = fmaf(ao0[4], xv1.x, o0);
      u0 = fmaf(au0[5], xv1.y, u0); o0 = fmaf(ao0[5], xv1.y, o0);
      u0 = fmaf(au0[6], xv1.z, u0); o0 = fmaf(ao0[6], xv1.z, o0);
      u0 = fmaf(au0[7], xv1.w, u0); o0 = fmaf(ao0[7], xv1.w, o0);
      u0 = fmaf(au0[8], x8, u0);    o0 = fmaf(ao0[8], x8, o0);
      x1[(size_t)(r0 + r) * 288 + c1] = gru_act(u0, o0);
      if (has2) {
        u1 = fmaf(au1[0], xv0.x, u1); o1 = fmaf(ao1[0], xv0.x, o1);
        u1 = fmaf(au1[1], xv0.y, u1); o1 = fmaf(ao1[1], xv0.y, o1);
        u1 = fmaf(au1[2], xv0.z, u1); o1 = fmaf(ao1[2], xv0.z, o1);
        u1 = fmaf(au1[3], xv0.w, u1); o1 = fmaf(ao1[3], xv0.w, o1);
        u1 = fmaf(au1[4], xv1.x, u1); o1 = fmaf(ao1[4], xv1.x, o1);
        u1 = fmaf(au1[5], xv1.y, u1); o1 = fmaf(ao1[5], xv1.y, o1);
        u1 = fmaf(au1[6], xv1.z, u1); o1 = fmaf(ao1[6], xv1.z, o1);
        u1 = fmaf(au1[7], xv1.w, u1); o1 = fmaf(ao1[7], xv1.w, o1);
        u1 = fmaf(au1[8], x8, u1);    o1 = fmaf(ao1[8], x8, o1);
        x1[(size_t)(r0 + r) * 288 + c2] = gru_act(u1, o1);
      }
    }
  }
  __syncthreads();   // x1 stores drained (vmcnt0 at barrier); L2-hot for readback

  // ---- L2: x1(global, L2-hot) x BT2(LDS-staged) -> x2. r6 step discipline ----
  {
    const char* x1b = (const char*)(x1 + (size_t)r0 * 288);
    unsigned avoff[4];
#pragma unroll
    for (int m = 0; m < 4; ++m)
      avoff[m] = (unsigned)(((m * 16 + lrow) * 288 + jc * 8) * 4);
    int rBoff[2][3];
#pragma unroll
    for (int g = 0; g < 2; ++g)
#pragma unroll
      for (int f = 0; f < 3; ++f) {
        int rb = g * 192 + (wid * 3 + f) * 16 + lrow;
        rBoff[g][f] = rb * 64 + ((jc ^ ((rb >> 1) & 3)) << 4);
      }

    f32x4 acc[4][2][3] = {};
    for (int s = 0; s < 27; ++s) {
      const int kt = s - (s / 9) * 9;
#pragma unroll
      for (int ci = 0; ci < 6; ++ci) *(bf16x8*)(Bl + wOffB2[ci]) = pf[ci];
      __syncthreads();   // Bl ready
      // issue A loads for THIS step (kt slice) + B loads for next step
      const unsigned uA = (unsigned)kt * 128u;
      float4 a0[4], a1[4];
#pragma unroll
      for (int m = 0; m < 4; ++m) {
        a0[m] = *(const float4*)(x1b + avoff[m] + uA);
        a1[m] = *(const float4*)(x1b + avoff[m] + uA + 16);
      }
      if (s < 26) {
        int ns = s + 1;
        unsigned uoff = (unsigned)(ns / 9) * 55296u + (unsigned)(ns % 9) * 32u;
#pragma unroll
        for (int ci = 0; ci < 6; ++ci)
          pf[ci] = *(const bf16x8*)(BT2 + uoff + toffB2[ci]);
      }
      bf16x8 bfr[2][3];
#pragma unroll
      for (int g = 0; g < 2; ++g)
#pragma unroll
        for (int f = 0; f < 3; ++f) bfr[g][f] = *(const bf16x8*)(Bl + rBoff[g][f]);
#pragma unroll
      for (int m = 0; m < 4; ++m) {
        union { uint4 u; bf16x8 v; } cv;
        cv.u.x = pack_trunc(a0[m].x, a0[m].y);
        cv.u.y = pack_trunc(a0[m].z, a0[m].w);
        cv.u.z = pack_trunc(a1[m].x, a1[m].y);
        cv.u.w = pack_trunc(a1[m].z, a1[m].w);
#pragma unroll
        for (int g = 0; g < 2; ++g)
#pragma unroll
          for (int f = 0; f < 3; ++f)
            acc[m][g][f] = __builtin_amdgcn_mfma_f32_16x16x32_bf16(
                cv.v, bfr[g][f], acc[m][g][f], 0, 0, 0);
      }
      if (kt == 8) {
        const int n0 = (s / 9) * 192;
#pragma unroll
        for (int m = 0; m < 4; ++m)
#pragma unroll
          for (int f = 0; f < 3; ++f) {
            int n = n0 + (wid * 3 + f) * 16 + lrow;
            float bU = b2u[n / 9], bO = b2o[n / 9];
            f32x4 uv = acc[m][0][f], ov = acc[m][1][f];
#pragma unroll
            for (int t = 0; t < 4; ++t) {
              int r = r0 + m * 16 + jc * 4 + t;
              x2[(size_t)r * 576 + n] = gru_act(uv[t] + bU, ov[t] + bO);
            }
            acc[m][0][f] = (f32x4){0.f, 0.f, 0.f, 0.f};
            acc[m][1][f] = (f32x4){0.f, 0.f, 0.f, 0.f};
          }
      }
      __syncthreads();   // Bl consumers done before next stage
    }
  }
  __syncthreads();   // x2 stores drained before L3 readback

  // stage dense weights (regions disjoint from x3l)
  for (int c = tid; c < 1296; c += 256) wl[c] = wd[c];
  if (tid < 9) blb[tid] = bd[tid];

  // ---- L3: x2(global, L2-hot) x BT3(LDS-staged). r6 step discipline ----
  {
    unsigned toffB3[5];
    int wOffB3[5];
#pragma unroll
    for (int j = 0; j < 5; ++j) {
      int c = j * 256 + tid;
      if (c < 1152) {
        int row = c >> 2, part = c & 3;
        toffB3[j] = (unsigned)row * 576u + part * 8;
        wOffB3[j] = row * 64 + ((part ^ ((row >> 1) & 3)) << 4);
      } else {
        toffB3[j] = 0; wOffB3[j] = 0;
      }
    }
    const char* x2b = (const char*)(x2 + (size_t)r0 * 576);
    unsigned avoff[4];
#pragma unroll
    for (int m = 0; m < 4; ++m)
      avoff[m] = (unsigned)(((m * 16 + lrow) * 576 + jc * 8) * 4);

    // issue kt=0 B loads (covered by wl staging)
    bf16x8 pb[5];
#pragma unroll
    for (int j = 0; j < 5; ++j)
      if (j * 256 + tid < 1152) pb[j] = *(const bf16x8*)(BT3 + toffB3[j]);

    int rBoff3[2][3];
#pragma unroll
    for (int g = 0; g < 2; ++g)
#pragma unroll
      for (int f = 0; f < 3; ++f) {
        int rb = g * 144 + (wid * 3 + f) * 16 + lrow;
        rBoff3[g][f] = rb * 64 + ((jc ^ ((rb >> 1) & 3)) << 4);
      }

    f32x4 acc[4][2][3] = {};
    for (int kt = 0; kt < 18; ++kt) {
#pragma unroll
      for (int j = 0; j < 5; ++j)
        if (j * 256 + tid < 1152) *(bf16x8*)(Bl + wOffB3[j]) = pb[j];
      __syncthreads();   // Bl ready
      const unsigned uA = (unsigned)kt * 128u;
      float4 a0[4], a1[4];
      if (wid < 3) {
#pragma unroll
        for (int m = 0; m < 4; ++m) {
          a0[m] = *(const float4*)(x2b + avoff[m] + uA);
          a1[m] = *(const float4*)(x2b + avoff[m] + uA + 16);
        }
      }
      if (kt < 17) {
        unsigned uoff = (unsigned)(kt + 1) * 32u;
#pragma unroll
        for (int j = 0; j < 5; ++j)
          if (j * 256 + tid < 1152) pb[j] = *(const bf16x8*)(BT3 + uoff + toffB3[j]);
      }
      if (wid < 3) {
        bf16x8 bfr[2][3];
#pragma unroll
        for (int g = 0; g < 2; ++g)
#pragma unroll
          for (int f = 0; f < 3; ++f)
            bfr[g][f] = *(const bf16x8*)(Bl + rBoff3[g][f]);
#pragma unroll
        for (int m = 0; m < 4; ++m) {
          union { uint4 u; bf16x8 v; } cv;
          cv.u.x = pack_trunc(a0[m].x, a0[m].y);
          cv.u.y = pack_trunc(a0[m].z, a0[m].w);
          cv.u.z = pack_trunc(a1[m].x, a1[m].y);
          cv.u.w = pack_trunc(a1[m].z, a1[m].w);
#pragma unroll
          for (int g = 0; g < 2; ++g)
#pragma unroll
            for (int f = 0; f < 3; ++f)
              acc[m][g][f] = __builtin_amdgcn_mfma_f32_16x16x32_bf16(
                  cv.v, bfr[g][f], acc[m][g][f], 0, 0, 0);
        }
      }
      __syncthreads();
    }
    // epilogue: act -> x3 global fp32 + x3l (LDS bf16, trunc)
    if (wid < 3) {
#pragma unroll
      for (int m = 0; m < 4; ++m)
#pragma unroll
        for (int f = 0; f < 3; ++f) {
          int n = (wid * 3 + f) * 16 + lrow;
          float bU = b3u[n / 9], bO = b3o[n / 9];
          f32x4 uv = acc[m][0][f], ov = acc[m][1][f];
#pragma unroll
          for (int t = 0; t < 4; ++t) {
            int r = m * 16 + jc * 4 + t;
            float v = gru_act(uv[t] + bU, ov[t] + bO);
            x3[(size_t)(r0 + r) * 144 + n] = v;
            x3l[r * 146 + n] = (unsigned short)(__float_as_uint(v) >> 16);
          }
        }
    }
  }
  __syncthreads();   // x3l + wl ready

  // ---- dense head: 3 waves, 3 cols each ----
  if (wid < 3) {
    int drow = lane;
    int jb = wid * 3;
    float s0 = blb[jb], s1 = blb[jb + 1], s2 = blb[jb + 2];
    for (int k = 0; k < 144; k += 2) {
      unsigned pr = *(const unsigned*)&x3l[drow * 146 + k];
      float v0 = __uint_as_float(pr << 16);
      float v1 = __uint_as_float(pr & 0xffff0000u);
      const float2 w0 = *(const float2*)&wl[jb * 144 + k];
      const float2 w1 = *(const float2*)&wl[(jb + 1) * 144 + k];
      const float2 w2 = *(const float2*)&wl[(jb + 2) * 144 + k];
      s0 = fmaf(v0, w0.x, s0); s0 = fmaf(v1, w0.y, s0);
      s1 = fmaf(v0, w1.x, s1); s1 = fmaf(v1, w1.y, s1);
      s2 = fmaf(v0, w2.x, s2); s2 = fmaf(v1, w2.y, s2);
    }
    size_t ob = (size_t)(r0 + drow) * 9 + jb;
    out[ob] = s0; out[ob + 1] = s1; out[ob + 2] = s2;
  }
}

extern "C" void kernel_launch(void* const* d_in, const int* in_sizes, int n_in,
                              void* d_out, int out_size, void* d_ws, size_t ws_size,
                              hipStream_t stream) {
  const float* inputs = (const float*)d_in[0];
  const float* wd  = (const float*)d_in[1];
  const float* bd  = (const float*)d_in[2];
  const float* w1u = (const float*)d_in[3];
  const float* b1u = (const float*)d_in[4];
  const float* w1o = (const float*)d_in[7];
  const float* b1o = (const float*)d_in[8];
  const float* w2u = (const float*)d_in[9];
  const float* b2u = (const float*)d_in[10];
  const float* w2o = (const float*)d_in[13];
  const float* b2o = (const float*)d_in[14];
  const float* w3u = (const float*)d_in[15];
  const float* b3u = (const float*)d_in[16];
  const float* w3o = (const float*)d_in[19];
  const float* b3o = (const float*)d_in[20];

  float* out = (float*)d_out;                    // [B][9]
  float* x1 = out + (size_t)BATCH * 9;           // [B][288]
  float* x2 = x1 + (size_t)BATCH * 288;          // [B][576]
  float* x3 = x2 + (size_t)BATCH * 576;          // [B][144]

  unsigned short* BT2 = (unsigned short*)d_ws;   // [2][576][288] bf16
  unsigned short* BT3 = BT2 + 331776;            // [2][144][576] bf16
  float* A1 = (float*)((char*)d_ws + 995328);    // [2][9][288] fp32

  build_bt<<<1296, 256, 0, stream>>>(w2u, w2o, BT2, 64, 32, 96);
  build_bt<<<648, 256, 0, stream>>>(w3u, w3o, BT3, 16, 64, 80);
  build_a1<<<21, 256, 0, stream>>>(w1u, w1o, A1);

  megafused<<<BATCH / 64, 256, 0, stream>>>(inputs, A1, b1u, b1o, BT2, b2u, b2o,
                                            BT3, b3u, b3o, wd, bd, x1, x2, x3, out);
}

// Round 11
// 197.079 us; speedup vs baseline: 4.6655x; 4.6655x over previous
//
#include <hip/hip_runtime.h>

#define BATCH 65536

typedef __attribute__((ext_vector_type(8))) short bf16x8;
typedef __attribute__((ext_vector_type(4))) float f32x4;

__device__ __forceinline__ unsigned short f2bf(float f) {
  unsigned int u = __float_as_uint(f);
  u += 0x7fffu + ((u >> 16) & 1u);   // RNE (one-time weight builds only)
  return (unsigned short)(u >> 16);
}
// trunc-pack 2 floats -> 1 dword of 2 bf16 (lo in low half), single v_perm_b32
__device__ __forceinline__ unsigned pack_trunc(float lo, float hi) {
  return __builtin_amdgcn_perm(__float_as_uint(hi), __float_as_uint(lo), 0x07060302u);
}

// tanh(o)*sigmoid(u): 2 exp + 1 rcp; lower-bound clamps keep it NaN-proof.
__device__ __forceinline__ float gru_act(float u, float o) {
  u = fmaxf(u, -60.0f);
  o = fmaxf(o, -30.0f);
  float a  = __expf(-u);
  float a2 = __expf(-2.0f * o);
  return (1.0f - a2) * __builtin_amdgcn_rcpf((1.0f + a) * (1.0f + a2));
}

// conv 3x3 SAME on 3x3 grid, unrolled tap value
__device__ __forceinline__ float conv_tap(const float* __restrict__ w, int co, int ci,
                                          int p, int q, int CINTOT) {
  int pi = p / 3, pj = p % 3, qi = q / 3, qj = q % 3;
  int di = qi - pi + 1, dj = qj - pj + 1;
  if ((unsigned)di < 3u && (unsigned)dj < 3u)
    return w[((co * CINTOT + ci) * 3 + di) * 3 + dj];
  return 0.0f;
}

// BT[g][n][k] bf16, n = co*9+p, k = ci*9+q
__global__ void build_bt(const float* __restrict__ wu, const float* __restrict__ wo,
                         unsigned short* __restrict__ BT, int COUT, int CINX, int CINTOT) {
  int NG = COUT * 9, K = CINX * 9;
  int total = 2 * NG * K;
  int e = blockIdx.x * 256 + threadIdx.x;
  if (e >= total) return;
  int g = e / (NG * K);
  int rem = e - g * (NG * K);
  int n = rem / K, k = rem - n * K;
  BT[e] = f2bf(conv_tap(g ? wo : wu, n / 9, k / 9, n % 9, k % 9, CINTOT));
}

// A1 transposed: [g][q][c], c = col n in [0,288), q = input tap in [0,9)
__global__ void build_a1(const float* __restrict__ wu, const float* __restrict__ wo,
                         float* __restrict__ A1) {
  int e = blockIdx.x * 256 + threadIdx.x;
  if (e >= 5184) return;
  int g = e / 2592;
  int rem = e - g * 2592;
  int q = rem / 288, c = rem - q * 288;
  A1[e] = conv_tap(g ? wo : wu, c / 9, 0, c % 9, q, 33);
}

// ---------------- LDS layout (bytes), lifetimes barrier-separated ----------------
// [0,40960)     x1l (L1 write .. L2 reads) | x3l [0,18688) (L3 epi .. dense)
// [20480,25664) wl (post-L2 .. dense)  [25664,25700) blb   (disjoint from x3l)
// [40960,65536) Bl 384x64 (L2) / 288x64 (L3) — WAVE-PRIVATE row slices
// [65536,68864) xl 64x13 f32 (L1 only)
#define OFF_X1L 0
#define OFF_X3L 0
#define OFF_WL 20480
#define OFF_BLB 25664
#define OFF_BL 40960
#define OFF_XL 65536
#define SMEM_BYTES 68864

__global__ __launch_bounds__(256, 2) void megafused(
    const float* __restrict__ xin, const float* __restrict__ A1,
    const float* __restrict__ b1u, const float* __restrict__ b1o,
    const unsigned short* __restrict__ BT2,
    const float* __restrict__ b2u, const float* __restrict__ b2o,
    const unsigned short* __restrict__ BT3,
    const float* __restrict__ b3u, const float* __restrict__ b3o,
    const float* __restrict__ wd, const float* __restrict__ bd,
    float* __restrict__ x1, float* __restrict__ x2,
    float* __restrict__ x3, float* __restrict__ out) {
  __shared__ __align__(16) char smem[SMEM_BYTES];
  char* x1l = smem + OFF_X1L;
  char* Bl = smem + OFF_BL;
  unsigned short* x3l = (unsigned short*)(smem + OFF_X3L);
  float* xl = (float*)(smem + OFF_XL);
  float* wl = (float*)(smem + OFF_WL);
  float* blb = (float*)(smem + OFF_BLB);

  const int tid = threadIdx.x;
  const int lane = tid & 63;
  const int wid = tid >> 6;
  const int lrow = lane & 15;
  const int jc = lane >> 4;
  const int r0 = blockIdx.x * 64;
  const int part = lane & 3;
  const int rlb = lane >> 2;         // 0..15, staging row-local base

  // L2 wave-private B staging: wave wid stages exactly rows {g*192+wid*48+[0,48)}
  // which are the only rows its MFMAs read -> NO barrier needed in the K-loop.
  unsigned toffB2[6];
  int wOffB2[6];
#pragma unroll
  for (int q = 0; q < 6; ++q) {
    int g = q / 3, rl = rlb + 16 * (q % 3);
    int grow = g * 576 + wid * 48 + rl;         // row in BT2 (gate1 at +576)
    toffB2[q] = (unsigned)grow * 288u + part * 8;
    int blrow = g * 192 + wid * 48 + rl;
    wOffB2[q] = blrow * 64 + ((part ^ ((blrow >> 1) & 3)) << 4);
  }

  // stage x input (stride 13 floats)
  for (int c = tid; c < 576; c += 256) xl[(c / 9) * 13 + (c % 9)] = xin[(size_t)r0 * 9 + c];
  __syncthreads();

  // issue L2 step-0 B loads (in flight across all of L1)
  bf16x8 pf[6];
#pragma unroll
  for (int q = 0; q < 6; ++q) pf[q] = *(const bf16x8*)(BT2 + toffB2[q]);

  // ---- L1: exact fp32, lanes = cols (r6 verbatim) ----
  {
    float au0[9], ao0[9], au1[9], ao1[9];
    const int c1 = tid, c2 = tid + 256;
    const bool has2 = (c2 < 288);
#pragma unroll
    for (int q = 0; q < 9; ++q) {
      au0[q] = A1[q * 288 + c1];
      ao0[q] = A1[2592 + q * 288 + c1];
      au1[q] = has2 ? A1[q * 288 + c2] : 0.0f;
      ao1[q] = has2 ? A1[2592 + q * 288 + c2] : 0.0f;
    }
    float bu0 = b1u[c1 / 9], bo0 = b1o[c1 / 9];
    float bu1 = has2 ? b1u[c2 / 9] : 0.0f;
    float bo1 = has2 ? b1o[c2 / 9] : 0.0f;
    for (int r = 0; r < 64; ++r) {
      const float4 xv0 = *(const float4*)&xl[r * 13];
      const float4 xv1 = *(const float4*)&xl[r * 13 + 4];
      const float x8 = xl[r * 13 + 8];
      float u0 = bu0, o0 = bo0, u1 = bu1, o1 = bo1;
      u0 = fmaf(au0[0], xv0.x, u0); o0 = fmaf(ao0[0], xv0.x, o0);
      u0 = fmaf(au0[1], xv0.y, u0); o0 = fmaf(ao0[1], xv0.y, o0);
      u0 = fmaf(au0[2], xv0.z, u0); o0 = fmaf(ao0[2], xv0.z, o0);
      u0 = fmaf(au0[3], xv0.w, u0); o0 = fmaf(ao0[3], xv0.w, o0);
      u0 = fmaf(au0[4], xv1.x, u0); o0 = fmaf(ao0[4], xv1.x, o0);
      u0 = fmaf(au0[5], xv1.y, u0); o0 = fmaf(ao0[5], xv1.y, o0);
      u0 = fmaf(au0[6], xv1.z, u0); o0 = fmaf(ao0[6], xv1.z, o0);
      u0 = fmaf(au0[7], xv1.w, u0); o0 = fmaf(ao0[7], xv1.w, o0);
      u0 = fmaf(au0[8], x8, u0);    o0 = fmaf(ao0[8], x8, o0);
      float v0 = gru_act(u0, o0);
      x1[(size_t)(r0 + r) * 288 + c1] = v0;
      *(unsigned short*)(x1l + r * 640 + (((c1 >> 3) ^ (r & 7)) << 4) + (c1 & 7) * 2) =
          (unsigned short)(__float_as_uint(v0) >> 16);
      if (has2) {
        u1 = fmaf(au1[0], xv0.x, u1); o1 = fmaf(ao1[0], xv0.x, o1);
        u1 = fmaf(au1[1], xv0.y, u1); o1 = fmaf(ao1[1], xv0.y, o1);
        u1 = fmaf(au1[2], xv0.z, u1); o1 = fmaf(ao1[2], xv0.z, o1);
        u1 = fmaf(au1[3], xv0.w, u1); o1 = fmaf(ao1[3], xv0.w, o1);
        u1 = fmaf(au1[4], xv1.x, u1); o1 = fmaf(ao1[4], xv1.x, o1);
        u1 = fmaf(au1[5], xv1.y, u1); o1 = fmaf(ao1[5], xv1.y, o1);
        u1 = fmaf(au1[6], xv1.z, u1); o1 = fmaf(ao1[6], xv1.z, o1);
        u1 = fmaf(au1[7], xv1.w, u1); o1 = fmaf(ao1[7], xv1.w, o1);
        u1 = fmaf(au1[8], x8, u1);    o1 = fmaf(ao1[8], x8, o1);
        float v1 = gru_act(u1, o1);
        x1[(size_t)(r0 + r) * 288 + c2] = v1;
        *(unsigned short*)(x1l + r * 640 + (((c2 >> 3) ^ (r & 7)) << 4) + (c2 & 7) * 2) =
            (unsigned short)(__float_as_uint(v1) >> 16);
      }
    }
  }
  __syncthreads();   // x1l visible to all waves (LAST barrier before L2 loop)

  // ---- L2: x1l x BT2 -> x2. 27 steps, wave-private staging, ZERO barriers ----
  {
    int rBoff[2][3];
#pragma unroll
    for (int g = 0; g < 2; ++g)
#pragma unroll
      for (int f = 0; f < 3; ++f) {
        int rb = g * 192 + (wid * 3 + f) * 16 + lrow;
        rBoff[g][f] = rb * 64 + ((jc ^ ((rb >> 1) & 3)) << 4);
      }
    const char* aBase[4];
    int aXor[4];
#pragma unroll
    for (int m = 0; m < 4; ++m) {
      int row = m * 16 + lrow;
      aBase[m] = x1l + row * 640;
      aXor[m] = row & 7;
    }

    // prologue: write step-0 tile to own slice (reg dep waits loads), load step-1
#pragma unroll
    for (int q = 0; q < 6; ++q) *(bf16x8*)(Bl + wOffB2[q]) = pf[q];
#pragma unroll
    for (int q = 0; q < 6; ++q) pf[q] = *(const bf16x8*)(BT2 + 32u + toffB2[q]);

    f32x4 acc[4][2][3] = {};
    for (int s = 0; s < 27; ++s) {
      const int kt = s - (s / 9) * 9;
      bf16x8 af[4];
      const int c8 = kt * 4 + jc;
#pragma unroll
      for (int m = 0; m < 4; ++m)
        af[m] = *(const bf16x8*)(aBase[m] + ((c8 ^ aXor[m]) << 4));
      bf16x8 bfr[2][3];
#pragma unroll
      for (int g = 0; g < 2; ++g)
#pragma unroll
        for (int f = 0; f < 3; ++f) bfr[g][f] = *(const bf16x8*)(Bl + rBoff[g][f]);
#pragma unroll
      for (int m = 0; m < 4; ++m)
#pragma unroll
        for (int g = 0; g < 2; ++g)
#pragma unroll
          for (int f = 0; f < 3; ++f)
            acc[m][g][f] = __builtin_amdgcn_mfma_f32_16x16x32_bf16(
                af[m], bfr[g][f], acc[m][g][f], 0, 0, 0);
      if (kt == 8) {
        const int n0 = (s / 9) * 192;
#pragma unroll
        for (int m = 0; m < 4; ++m)
#pragma unroll
          for (int f = 0; f < 3; ++f) {
            int n = n0 + (wid * 3 + f) * 16 + lrow;
            float bU = b2u[n / 9], bO = b2o[n / 9];
            f32x4 uv = acc[m][0][f], ov = acc[m][1][f];
#pragma unroll
            for (int t = 0; t < 4; ++t) {
              int r = r0 + m * 16 + jc * 4 + t;
              x2[(size_t)r * 576 + n] = gru_act(uv[t] + bU, ov[t] + bO);
            }
            acc[m][0][f] = (f32x4){0.f, 0.f, 0.f, 0.f};
            acc[m][1][f] = (f32x4){0.f, 0.f, 0.f, 0.f};
          }
      }
      // wave-local: reads of this slice (in-order DS) precede the overwrite
      if (s < 26) {
#pragma unroll
        for (int q = 0; q < 6; ++q) *(bf16x8*)(Bl + wOffB2[q]) = pf[q];
        if (s < 25) {
          int ns = s + 2;
          unsigned uoff = (unsigned)(ns / 9) * 55296u + (unsigned)(ns % 9) * 32u;
#pragma unroll
          for (int q = 0; q < 6; ++q)
            pf[q] = *(const bf16x8*)(BT2 + uoff + toffB2[q]);
        }
      }
    }
  }

  // issue L3 B step-0 loads before the drain barrier (land by barrier exit)
  bf16x8 pb[6];
  unsigned toffB3[6];
  int wOffB3[6];
  if (wid < 3) {
#pragma unroll
    for (int q = 0; q < 6; ++q) {
      int g = q / 3, rl = rlb + 16 * (q % 3);
      toffB3[q] = (unsigned)(g * 144 + wid * 48 + rl) * 576u + part * 8;
      int blrow = g * 144 + wid * 48 + rl;
      wOffB3[q] = blrow * 64 + ((part ^ ((blrow >> 1) & 3)) << 4);
      pb[q] = *(const bf16x8*)(BT3 + toffB3[q]);
    }
  }
  __syncthreads();   // drains x2 stores; x1l dead beyond here

  // stage dense weights (disjoint from x3l; visible to dense via post-L3 barrier)
  for (int c = tid; c < 1296; c += 256) wl[c] = wd[c];
  if (tid < 9) blb[tid] = bd[tid];

  // ---- L3: x2(global, streamed once) x BT3(wave-private LDS). ZERO barriers ----
  if (wid < 3) {
    int rBoff3[2][3];
#pragma unroll
    for (int g = 0; g < 2; ++g)
#pragma unroll
      for (int f = 0; f < 3; ++f) {
        int rb = g * 144 + (wid * 3 + f) * 16 + lrow;
        rBoff3[g][f] = rb * 64 + ((jc ^ ((rb >> 1) & 3)) << 4);
      }
    const char* x2b = (const char*)(x2 + (size_t)r0 * 576);
    unsigned avoff[4];
#pragma unroll
    for (int m = 0; m < 4; ++m)
      avoff[m] = (unsigned)(((m * 16 + lrow) * 576 + jc * 8) * 4);

    // prologue: write step-0 tile, load step-1
#pragma unroll
    for (int q = 0; q < 6; ++q) *(bf16x8*)(Bl + wOffB3[q]) = pb[q];
#pragma unroll
    for (int q = 0; q < 6; ++q) pb[q] = *(const bf16x8*)(BT3 + 32u + toffB3[q]);

    f32x4 acc[4][2][3] = {};
    for (int kt = 0; kt < 18; ++kt) {
      const unsigned uA = (unsigned)kt * 128u;
      float4 a0[4], a1[4];
#pragma unroll
      for (int m = 0; m < 4; ++m) {
        a0[m] = *(const float4*)(x2b + avoff[m] + uA);
        a1[m] = *(const float4*)(x2b + avoff[m] + uA + 16);
      }
      bf16x8 bfr[2][3];
#pragma unroll
      for (int g = 0; g < 2; ++g)
#pragma unroll
        for (int f = 0; f < 3; ++f) bfr[g][f] = *(const bf16x8*)(Bl + rBoff3[g][f]);
#pragma unroll
      for (int m = 0; m < 4; ++m) {
        union { uint4 u; bf16x8 v; } cv;
        cv.u.x = pack_trunc(a0[m].x, a0[m].y);
        cv.u.y = pack_trunc(a0[m].z, a0[m].w);
        cv.u.z = pack_trunc(a1[m].x, a1[m].y);
        cv.u.w = pack_trunc(a1[m].z, a1[m].w);
#pragma unroll
        for (int g = 0; g < 2; ++g)
#pragma unroll
          for (int f = 0; f < 3; ++f)
            acc[m][g][f] = __builtin_amdgcn_mfma_f32_16x16x32_bf16(
                cv.v, bfr[g][f], acc[m][g][f], 0, 0, 0);
      }
      if (kt < 17) {
#pragma unroll
        for (int q = 0; q < 6; ++q) *(bf16x8*)(Bl + wOffB3[q]) = pb[q];
        if (kt < 16) {
          unsigned uoff = (unsigned)(kt + 2) * 32u;
#pragma unroll
          for (int q = 0; q < 6; ++q)
            pb[q] = *(const bf16x8*)(BT3 + uoff + toffB3[q]);
        }
      }
    }
    // epilogue: act -> x3 global fp32 + x3l (LDS bf16, trunc)
#pragma unroll
    for (int m = 0; m < 4; ++m)
#pragma unroll
      for (int f = 0; f < 3; ++f) {
        int n = (wid * 3 + f) * 16 + lrow;
        float bU = b3u[n / 9], bO = b3o[n / 9];
        f32x4 uv = acc[m][0][f], ov = acc[m][1][f];
#pragma unroll
        for (int t = 0; t < 4; ++t) {
          int r = m * 16 + jc * 4 + t;
          float v = gru_act(uv[t] + bU, ov[t] + bO);
          x3[(size_t)(r0 + r) * 144 + n] = v;
          x3l[r * 146 + n] = (unsigned short)(__float_as_uint(v) >> 16);
        }
      }
  }
  __syncthreads();   // x3l + wl ready (wave 3 waits here)

  // ---- dense head: 3 waves, 3 cols each ----
  if (wid < 3) {
    int drow = lane;
    int jb = wid * 3;
    float s0 = blb[jb], s1 = blb[jb + 1], s2 = blb[jb + 2];
    for (int k = 0; k < 144; k += 2) {
      unsigned pr = *(const unsigned*)&x3l[drow * 146 + k];
      float v0 = __uint_as_float(pr << 16);
      float v1 = __uint_as_float(pr & 0xffff0000u);
      const float2 w0 = *(const float2*)&wl[jb * 144 + k];
      const float2 w1 = *(const float2*)&wl[(jb + 1) * 144 + k];
      const float2 w2 = *(const float2*)&wl[(jb + 2) * 144 + k];
      s0 = fmaf(v0, w0.x, s0); s0 = fmaf(v1, w0.y, s0);
      s1 = fmaf(v0, w1.x, s1); s1 = fmaf(v1, w1.y, s1);
      s2 = fmaf(v0, w2.x, s2); s2 = fmaf(v1, w2.y, s2);
    }
    size_t ob = (size_t)(r0 + drow) * 9 + jb;
    out[ob] = s0; out[ob + 1] = s1; out[ob + 2] = s2;
  }
}

extern "C" void kernel_launch(void* const* d_in, const int* in_sizes, int n_in,
                              void* d_out, int out_size, void* d_ws, size_t ws_size,
                              hipStream_t stream) {
  const float* inputs = (const float*)d_in[0];
  const float* wd  = (const float*)d_in[1];
  const float* bd  = (const float*)d_in[2];
  const float* w1u = (const float*)d_in[3];
  const float* b1u = (const float*)d_in[4];
  const float* w1o = (const float*)d_in[7];
  const float* b1o = (const float*)d_in[8];
  const float* w2u = (const float*)d_in[9];
  const float* b2u = (const float*)d_in[10];
  const float* w2o = (const float*)d_in[13];
  const float* b2o = (const float*)d_in[14];
  const float* w3u = (const float*)d_in[15];
  const float* b3u = (const float*)d_in[16];
  const float* w3o = (const float*)d_in[19];
  const float* b3o = (const float*)d_in[20];

  float* out = (float*)d_out;                    // [B][9]
  float* x1 = out + (size_t)BATCH * 9;           // [B][288]
  float* x2 = x1 + (size_t)BATCH * 288;          // [B][576]
  float* x3 = x2 + (size_t)BATCH * 576;          // [B][144]

  unsigned short* BT2 = (unsigned short*)d_ws;   // [2][576][288] bf16
  unsigned short* BT3 = BT2 + 331776;            // [2][144][576] bf16
  float* A1 = (float*)((char*)d_ws + 995328);    // [2][9][288] fp32

  build_bt<<<1296, 256, 0, stream>>>(w2u, w2o, BT2, 64, 32, 96);
  build_bt<<<648, 256, 0, stream>>>(w3u, w3o, BT3, 16, 64, 80);
  build_a1<<<21, 256, 0, stream>>>(w1u, w1o, A1);

  megafused<<<BATCH / 64, 256, 0, stream>>>(inputs, A1, b1u, b1o, BT2, b2u, b2o,
                                            BT3, b3u, b3o, wd, bd, x1, x2, x3, out);
}

// Round 12
// 154.759 us; speedup vs baseline: 5.9413x; 1.2735x over previous
//
#include <hip/hip_runtime.h>

#define BATCH 65536

typedef __attribute__((ext_vector_type(8))) short bf16x8;
typedef __attribute__((ext_vector_type(4))) float f32x4;

__device__ __forceinline__ unsigned short f2bf(float f) {
  unsigned int u = __float_as_uint(f);
  u += 0x7fffu + ((u >> 16) & 1u);   // RNE (one-time weight builds only)
  return (unsigned short)(u >> 16);
}
// trunc-pack 2 floats -> 1 dword of 2 bf16 (lo in low half), single v_perm_b32
__device__ __forceinline__ unsigned pack_trunc(float lo, float hi) {
  return __builtin_amdgcn_perm(__float_as_uint(hi), __float_as_uint(lo), 0x07060302u);
}

// tanh(o)*sigmoid(u): 2 exp + 1 rcp; lower-bound clamps keep it NaN-proof.
__device__ __forceinline__ float gru_act(float u, float o) {
  u = fmaxf(u, -60.0f);
  o = fmaxf(o, -30.0f);
  float a  = __expf(-u);
  float a2 = __expf(-2.0f * o);
  return (1.0f - a2) * __builtin_amdgcn_rcpf((1.0f + a) * (1.0f + a2));
}

// conv 3x3 SAME on 3x3 grid, unrolled tap value
__device__ __forceinline__ float conv_tap(const float* __restrict__ w, int co, int ci,
                                          int p, int q, int CINTOT) {
  int pi = p / 3, pj = p % 3, qi = q / 3, qj = q % 3;
  int di = qi - pi + 1, dj = qj - pj + 1;
  if ((unsigned)di < 3u && (unsigned)dj < 3u)
    return w[((co * CINTOT + ci) * 3 + di) * 3 + dj];
  return 0.0f;
}

// BT[g][n][k] bf16, n = co*9+p, k = ci*9+q
__global__ void build_bt(const float* __restrict__ wu, const float* __restrict__ wo,
                         unsigned short* __restrict__ BT, int COUT, int CINX, int CINTOT) {
  int NG = COUT * 9, K = CINX * 9;
  int total = 2 * NG * K;
  int e = blockIdx.x * 256 + threadIdx.x;
  if (e >= total) return;
  int g = e / (NG * K);
  int rem = e - g * (NG * K);
  int n = rem / K, k = rem - n * K;
  BT[e] = f2bf(conv_tap(g ? wo : wu, n / 9, k / 9, n % 9, k % 9, CINTOT));
}

// BT1[g][n][k32] bf16: layer-1 weights, K padded 9->32 with zeros
__global__ void build_bt1(const float* __restrict__ wu, const float* __restrict__ wo,
                          unsigned short* __restrict__ BT1) {
  int e = blockIdx.x * 256 + threadIdx.x;
  if (e >= 18432) return;
  int g = e / 9216;
  int rem = e - g * 9216;
  int n = rem / 32, k = rem - n * 32;
  float v = (k < 9) ? conv_tap(g ? wo : wu, n / 9, 0, n % 9, k, 33) : 0.0f;
  BT1[e] = f2bf(v);
}

// ---------------- LDS layout (bytes), lifetimes barrier-separated ----------------
// [0,40960)     x1l (L1-GEMM epi .. L2 reads) | x3l [0,18688) (L3 epi .. dense)
// [20480,25664) wl (post-L2 .. dense)  [25664,25700) blb  (disjoint from x3l)
// [40960,65536) Bl 288/384 rows x 64B (L1/L3 / L2)
// [65536,74752) xl2 64 x 36 f32 (L1 only) | Al 64x64 (L3) overlays start
#define OFF_X1L 0
#define OFF_X3L 0
#define OFF_WL 20480
#define OFF_BLB 25664
#define OFF_BL 40960
#define OFF_XL2 65536
#define OFF_AL 65536
#define SMEM_BYTES 74752

__global__ __launch_bounds__(256, 2) void megafused(
    const float* __restrict__ xin, const unsigned short* __restrict__ BT1,
    const float* __restrict__ b1u, const float* __restrict__ b1o,
    const unsigned short* __restrict__ BT2,
    const float* __restrict__ b2u, const float* __restrict__ b2o,
    const unsigned short* __restrict__ BT3,
    const float* __restrict__ b3u, const float* __restrict__ b3o,
    const float* __restrict__ wd, const float* __restrict__ bd,
    float* __restrict__ x1, float* __restrict__ x2,
    float* __restrict__ x3, float* __restrict__ out) {
  __shared__ __align__(16) char smem[SMEM_BYTES];
  char* x1l = smem + OFF_X1L;
  char* Bl = smem + OFF_BL;
  char* Al = smem + OFF_AL;
  unsigned short* x3l = (unsigned short*)(smem + OFF_X3L);
  float* xl2 = (float*)(smem + OFF_XL2);
  float* wl = (float*)(smem + OFF_WL);
  float* blb = (float*)(smem + OFF_BLB);

  const int tid = threadIdx.x;
  const int lane = tid & 63;
  const int wid = tid >> 6;
  const int lrow = lane & 15;
  const int jc = lane >> 4;
  const int r0 = blockIdx.x * 64;
  const int srow = tid >> 2, spart = tid & 3;   // staging coords

  // L2 B-staging thread-constants (r6 verbatim): 6 chunks/thread, rows in [0,384)
  unsigned toffB2[6];
  int wOffB2[6];
#pragma unroll
  for (int ci = 0; ci < 6; ++ci) {
    int row = ci * 64 + srow;
    int bg = (row < 192) ? row : (384 + row);   // BT2 row (gate1 at 576)
    toffB2[ci] = (unsigned)bg * 288u + spart * 8;
    wOffB2[ci] = row * 64 + ((spart ^ ((row >> 1) & 3)) << 4);
  }
  // L1/L3-style guarded staging constants (288 rows x 4 parts = 1152 chunks)
  unsigned toffB1[5];
  int wOffG[5];
#pragma unroll
  for (int j = 0; j < 5; ++j) {
    int c = j * 256 + tid;
    if (c < 1152) {
      int row = c >> 2, p = c & 3;
      int g = row >= 144, nloc = row - (g ? 144 : 0);
      toffB1[j] = (unsigned)(g * 288 + nloc) * 32u + p * 8;   // BT1 shorts (+ch*4608)
      wOffG[j] = row * 64 + ((p ^ ((row >> 1) & 3)) << 4);
    } else {
      toffB1[j] = 0; wOffG[j] = 0;
    }
  }

  // stage x input into zero-padded xl2[64][36] (K padded 9->32; cols 9..35 = 0)
  for (int c = tid; c < 2304; c += 256) {
    int row = c / 36, col = c - row * 36;
    xl2[c] = (col < 9) ? xin[(size_t)(r0 + row) * 9 + col] : 0.0f;
  }
  // issue L1 chunk-0 B loads (consumed after the barrier)
  bf16x8 pb[5];
#pragma unroll
  for (int j = 0; j < 5; ++j)
    if (j * 256 + tid < 1152) pb[j] = *(const bf16x8*)(BT1 + toffB1[j]);
  __syncthreads();   // xl2 visible

  // A-fragments for L1 (loop-invariant across both chunks)
  bf16x8 afx[4];
#pragma unroll
  for (int m = 0; m < 4; ++m) {
    const float* xr = xl2 + (m * 16 + lrow) * 36 + jc * 8;
    float4 a0 = *(const float4*)xr;
    float4 a1 = *(const float4*)(xr + 4);
    union { uint4 u; bf16x8 v; } cv;
    cv.u.x = pack_trunc(a0.x, a0.y);
    cv.u.y = pack_trunc(a0.z, a0.w);
    cv.u.z = pack_trunc(a1.x, a1.y);
    cv.u.w = pack_trunc(a1.z, a1.w);
    afx[m] = cv.v;
  }
  // frag-read offsets shared by L1 and L3 (N=144/gate layout)
  int rBoffG[2][3];
#pragma unroll
  for (int g = 0; g < 2; ++g)
#pragma unroll
    for (int f = 0; f < 3; ++f) {
      int rb = g * 144 + (wid * 3 + f) * 16 + lrow;
      rBoffG[g][f] = rb * 64 + ((jc ^ ((rb >> 1) & 3)) << 4);
    }

  bf16x8 pf[6];
  // ---- L1 as GEMM: 2 n-chunks of 144 cols/gate, K=32 (1 step each) ----
#pragma unroll
  for (int ch = 0; ch < 2; ++ch) {
#pragma unroll
    for (int j = 0; j < 5; ++j)
      if (j * 256 + tid < 1152) *(bf16x8*)(Bl + wOffG[j]) = pb[j];
    // issue next tile: ch0 -> BT1 chunk1; ch1 -> BT2 step-0 (covers into L2)
    if (ch == 0) {
#pragma unroll
      for (int j = 0; j < 5; ++j)
        if (j * 256 + tid < 1152) pb[j] = *(const bf16x8*)(BT1 + 4608u + toffB1[j]);
    } else {
#pragma unroll
      for (int q = 0; q < 6; ++q) pf[q] = *(const bf16x8*)(BT2 + toffB2[q]);
    }
    __syncthreads();   // Bl ready
    if (wid < 3) {
      f32x4 acc[4][2][3] = {};
      bf16x8 bfr[2][3];
#pragma unroll
      for (int g = 0; g < 2; ++g)
#pragma unroll
        for (int f = 0; f < 3; ++f) bfr[g][f] = *(const bf16x8*)(Bl + rBoffG[g][f]);
#pragma unroll
      for (int m = 0; m < 4; ++m)
#pragma unroll
        for (int g = 0; g < 2; ++g)
#pragma unroll
          for (int f = 0; f < 3; ++f)
            acc[m][g][f] = __builtin_amdgcn_mfma_f32_16x16x32_bf16(
                afx[m], bfr[g][f], acc[m][g][f], 0, 0, 0);
      // epilogue: act -> x1 global fp32 + x1l bf16 (trunc)
#pragma unroll
      for (int m = 0; m < 4; ++m)
#pragma unroll
        for (int f = 0; f < 3; ++f) {
          int n = ch * 144 + (wid * 3 + f) * 16 + lrow;
          float bU = b1u[n / 9], bO = b1o[n / 9];
          f32x4 uv = acc[m][0][f], ov = acc[m][1][f];
#pragma unroll
          for (int t = 0; t < 4; ++t) {
            int r = m * 16 + jc * 4 + t;
            float v = gru_act(uv[t] + bU, ov[t] + bO);
            x1[(size_t)(r0 + r) * 288 + n] = v;
            *(unsigned short*)(x1l + r * 640 + (((n >> 3) ^ (r & 7)) << 4) + (n & 7) * 2) =
                (unsigned short)(__float_as_uint(v) >> 16);
          }
        }
    }
    __syncthreads();   // Bl consumers done; (ch1) x1l fully visible
  }

  // ---- L2: x1l(bf16) x BT2 -> x2 global fp32 (r6 verbatim, 27 steps) ----
  {
    int rBoff[2][3];
#pragma unroll
    for (int g = 0; g < 2; ++g)
#pragma unroll
      for (int f = 0; f < 3; ++f) {
        int rb = g * 192 + (wid * 3 + f) * 16 + lrow;
        rBoff[g][f] = rb * 64 + ((jc ^ ((rb >> 1) & 3)) << 4);
      }
    const char* aBase[4];
    int aXor[4];
#pragma unroll
    for (int m = 0; m < 4; ++m) {
      int row = m * 16 + lrow;
      aBase[m] = x1l + row * 640;
      aXor[m] = row & 7;
    }

    f32x4 acc[4][2][3] = {};
    for (int s = 0; s < 27; ++s) {
      const int kt = s - (s / 9) * 9;
#pragma unroll
      for (int ci = 0; ci < 6; ++ci) *(bf16x8*)(Bl + wOffB2[ci]) = pf[ci];
      __syncthreads();   // Bl ready
      if (s < 26) {
        int ns = s + 1;
        unsigned uoff = (unsigned)(ns / 9) * 55296u + (unsigned)(ns % 9) * 32u;
#pragma unroll
        for (int ci = 0; ci < 6; ++ci)
          pf[ci] = *(const bf16x8*)(BT2 + uoff + toffB2[ci]);
      }
      bf16x8 af[4];
      const int c8 = kt * 4 + jc;
#pragma unroll
      for (int m = 0; m < 4; ++m)
        af[m] = *(const bf16x8*)(aBase[m] + ((c8 ^ aXor[m]) << 4));
      bf16x8 bfr[2][3];
#pragma unroll
      for (int g = 0; g < 2; ++g)
#pragma unroll
        for (int f = 0; f < 3; ++f) bfr[g][f] = *(const bf16x8*)(Bl + rBoff[g][f]);
#pragma unroll
      for (int m = 0; m < 4; ++m)
#pragma unroll
        for (int g = 0; g < 2; ++g)
#pragma unroll
          for (int f = 0; f < 3; ++f)
            acc[m][g][f] = __builtin_amdgcn_mfma_f32_16x16x32_bf16(
                af[m], bfr[g][f], acc[m][g][f], 0, 0, 0);
      if (kt == 8) {
        const int n0 = (s / 9) * 192;
#pragma unroll
        for (int m = 0; m < 4; ++m)
#pragma unroll
          for (int f = 0; f < 3; ++f) {
            int n = n0 + (wid * 3 + f) * 16 + lrow;
            float bU = b2u[n / 9], bO = b2o[n / 9];
            f32x4 uv = acc[m][0][f], ov = acc[m][1][f];
#pragma unroll
            for (int t = 0; t < 4; ++t) {
              int r = r0 + m * 16 + jc * 4 + t;
              x2[(size_t)r * 576 + n] = gru_act(uv[t] + bU, ov[t] + bO);
            }
            acc[m][0][f] = (f32x4){0.f, 0.f, 0.f, 0.f};
            acc[m][1][f] = (f32x4){0.f, 0.f, 0.f, 0.f};
          }
      }
      __syncthreads();   // Bl consumers done before next stage
    }
  }
  __syncthreads();   // x2 stores drained before L3 readback; x1l dead

  // stage dense weights (regions disjoint from x3l)
  for (int c = tid; c < 1296; c += 256) wl[c] = wd[c];
  if (tid < 9) blb[tid] = bd[tid];

  // ---- L3: x2 (L2-hot readback) x BT3, depth-1 prefetch of A and B (r6 verbatim) ----
  {
    unsigned toffB3[5];
#pragma unroll
    for (int j = 0; j < 5; ++j) {
      int c = j * 256 + tid;
      toffB3[j] = (c < 1152) ? ((unsigned)(c >> 2) * 576u + (c & 3) * 8) : 0u;
    }
    const float* pA = x2 + (size_t)(r0 + srow) * 576 + spart * 8;
    char* wAl = Al + srow * 64 + ((spart ^ ((srow >> 1) & 3)) << 4);

    // issue kt=0 loads (covered by wl staging above)
    float4 pa0 = *(const float4*)pA;
    float4 pa1 = *(const float4*)(pA + 4);
    bf16x8 pb3[5];
#pragma unroll
    for (int j = 0; j < 5; ++j)
      if (j * 256 + tid < 1152) pb3[j] = *(const bf16x8*)(BT3 + toffB3[j]);

    const char* rA3[4];
#pragma unroll
    for (int m = 0; m < 4; ++m) {
      int row = m * 16 + lrow;
      rA3[m] = Al + row * 64 + ((jc ^ ((row >> 1) & 3)) << 4);
    }

    f32x4 acc[4][2][3] = {};
    for (int kt = 0; kt < 18; ++kt) {
      uint4 h;
      h.x = pack_trunc(pa0.x, pa0.y);
      h.y = pack_trunc(pa0.z, pa0.w);
      h.z = pack_trunc(pa1.x, pa1.y);
      h.w = pack_trunc(pa1.z, pa1.w);
      *(uint4*)wAl = h;
#pragma unroll
      for (int j = 0; j < 5; ++j)
        if (j * 256 + tid < 1152) *(bf16x8*)(Bl + wOffG[j]) = pb3[j];
      __syncthreads();   // Al/Bl ready
      if (kt < 17) {
        const float* gp = pA + (kt + 1) * 32;
        pa0 = *(const float4*)gp;
        pa1 = *(const float4*)(gp + 4);
        unsigned uoff = (unsigned)(kt + 1) * 32u;
#pragma unroll
        for (int j = 0; j < 5; ++j)
          if (j * 256 + tid < 1152) pb3[j] = *(const bf16x8*)(BT3 + uoff + toffB3[j]);
      }
      if (wid < 3) {
        bf16x8 af[4];
#pragma unroll
        for (int m = 0; m < 4; ++m) af[m] = *(const bf16x8*)rA3[m];
        bf16x8 bfr[2][3];
#pragma unroll
        for (int g = 0; g < 2; ++g)
#pragma unroll
          for (int f = 0; f < 3; ++f) bfr[g][f] = *(const bf16x8*)(Bl + rBoffG[g][f]);
#pragma unroll
        for (int m = 0; m < 4; ++m)
#pragma unroll
          for (int g = 0; g < 2; ++g)
#pragma unroll
            for (int f = 0; f < 3; ++f)
              acc[m][g][f] = __builtin_amdgcn_mfma_f32_16x16x32_bf16(
                  af[m], bfr[g][f], acc[m][g][f], 0, 0, 0);
      }
      __syncthreads();
    }
    // epilogue: act -> x3 global fp32 + x3l (LDS bf16, trunc)
    if (wid < 3) {
#pragma unroll
      for (int m = 0; m < 4; ++m)
#pragma unroll
        for (int f = 0; f < 3; ++f) {
          int n = (wid * 3 + f) * 16 + lrow;
          float bU = b3u[n / 9], bO = b3o[n / 9];
          f32x4 uv = acc[m][0][f], ov = acc[m][1][f];
#pragma unroll
          for (int t = 0; t < 4; ++t) {
            int r = m * 16 + jc * 4 + t;
            float v = gru_act(uv[t] + bU, ov[t] + bO);
            x3[(size_t)(r0 + r) * 144 + n] = v;
            x3l[r * 146 + n] = (unsigned short)(__float_as_uint(v) >> 16);
          }
        }
    }
  }
  __syncthreads();   // x3l + wl ready

  // ---- dense head: 3 waves, 3 cols each ----
  if (wid < 3) {
    int drow = lane;
    int jb = wid * 3;
    float s0 = blb[jb], s1 = blb[jb + 1], s2 = blb[jb + 2];
    for (int k = 0; k < 144; k += 2) {
      unsigned pr = *(const unsigned*)&x3l[drow * 146 + k];
      float v0 = __uint_as_float(pr << 16);
      float v1 = __uint_as_float(pr & 0xffff0000u);
      const float2 w0 = *(const float2*)&wl[jb * 144 + k];
      const float2 w1 = *(const float2*)&wl[(jb + 1) * 144 + k];
      const float2 w2 = *(const float2*)&wl[(jb + 2) * 144 + k];
      s0 = fmaf(v0, w0.x, s0); s0 = fmaf(v1, w0.y, s0);
      s1 = fmaf(v0, w1.x, s1); s1 = fmaf(v1, w1.y, s1);
      s2 = fmaf(v0, w2.x, s2); s2 = fmaf(v1, w2.y, s2);
    }
    size_t ob = (size_t)(r0 + drow) * 9 + jb;
    out[ob] = s0; out[ob + 1] = s1; out[ob + 2] = s2;
  }
}

extern "C" void kernel_launch(void* const* d_in, const int* in_sizes, int n_in,
                              void* d_out, int out_size, void* d_ws, size_t ws_size,
                              hipStream_t stream) {
  const float* inputs = (const float*)d_in[0];
  const float* wd  = (const float*)d_in[1];
  const float* bd  = (const float*)d_in[2];
  const float* w1u = (const float*)d_in[3];
  const float* b1u = (const float*)d_in[4];
  const float* w1o = (const float*)d_in[7];
  const float* b1o = (const float*)d_in[8];
  const float* w2u = (const float*)d_in[9];
  const float* b2u = (const float*)d_in[10];
  const float* w2o = (const float*)d_in[13];
  const float* b2o = (const float*)d_in[14];
  const float* w3u = (const float*)d_in[15];
  const float* b3u = (const float*)d_in[16];
  const float* w3o = (const float*)d_in[19];
  const float* b3o = (const float*)d_in[20];

  float* out = (float*)d_out;                    // [B][9]
  float* x1 = out + (size_t)BATCH * 9;           // [B][288]
  float* x2 = x1 + (size_t)BATCH * 288;          // [B][576]
  float* x3 = x2 + (size_t)BATCH * 576;          // [B][144]

  unsigned short* BT2 = (unsigned short*)d_ws;   // [2][576][288] bf16
  unsigned short* BT3 = BT2 + 331776;            // [2][144][576] bf16
  unsigned short* BT1 = BT3 + 165888;            // [2][288][32]  bf16

  build_bt<<<1296, 256, 0, stream>>>(w2u, w2o, BT2, 64, 32, 96);
  build_bt<<<648, 256, 0, stream>>>(w3u, w3o, BT3, 16, 64, 80);
  build_bt1<<<72, 256, 0, stream>>>(w1u, w1o, BT1);

  megafused<<<BATCH / 64, 256, 0, stream>>>(inputs, BT1, b1u, b1o, BT2, b2u, b2o,
                                            BT3, b3u, b3o, wd, bd, x1, x2, x3, out);
}